// Round 5
// baseline (163.329 us; speedup 1.0000x reference)
//
#include <hip/hip_runtime.h>

#define T_TOK 8192
#define D_DIM 128
#define N_NEU 4096
#define RPC 96             // rows per chunk in combo phase
#define NCHUNK 256         // 24576 / RPC  -> one block per CU

// ---------------------------------------------------------------------------
// Kernel 1: blocks 0..15  -> acts (last 16 tokens) + window means w=1,2,4,8,16
//           block 16      -> qkv -> 32x32 attention -> mean -> LayerNorm -> yvec
// (verified round 3/4: absmax 6.1e-05; this round: unroll-4 on load loops)
// ---------------------------------------------------------------------------
struct SmemAttn {
    float xs[32][128];   // last-32 tokens; later overwritten with v
    float qs[32][128];
    float kt[128][33];   // k transposed, padded (bank-conflict-free)
    float ps[32][33];
    float pbar[32];
    float mvec[128];
    float red[2];
};
union Smem1 {
    float xs16[16][128];
    SmemAttn attn;
};

__global__ void means_attn_kernel(
    const float* __restrict__ x,
    const float* __restrict__ neuronW, const float* __restrict__ neuronB,
    const float* __restrict__ Wq, const float* __restrict__ bq,
    const float* __restrict__ Wk, const float* __restrict__ bk,
    const float* __restrict__ Wv, const float* __restrict__ bv,
    const float* __restrict__ ln_g, const float* __restrict__ ln_b,
    float* __restrict__ means,   // [5][4096]
    float* __restrict__ yvec)    // [128]
{
    __shared__ Smem1 sm;
    const int tid = threadIdx.x;
    const int bid = blockIdx.x;

    if (bid < 16) {
        int n = bid * 256 + tid;
        for (int idx = tid; idx < 16 * 128; idx += 256) {
            int t = idx >> 7, d = idx & 127;
            sm.xs16[t][d] = x[(size_t)(T_TOK - 16 + t) * D_DIM + d];
        }
        __syncthreads();
        float acc[16];
        float bias = neuronB[n];
#pragma unroll
        for (int t = 0; t < 16; ++t) acc[t] = bias;
#pragma unroll 4
        for (int d = 0; d < 128; ++d) {
            float w = neuronW[(size_t)d * N_NEU + n];
#pragma unroll
            for (int t = 0; t < 16; ++t) acc[t] += sm.xs16[t][d] * w;
        }
#pragma unroll
        for (int t = 0; t < 16; ++t) acc[t] = tanhf(acc[t]);  // |tanh|<=1 => clip no-op
        float s1 = acc[15];
        float s2 = s1 + acc[14];
        float s4 = s2 + acc[13] + acc[12];
        float s8 = s4 + acc[11] + acc[10] + acc[9] + acc[8];
        float s16 = s8 + acc[7] + acc[6] + acc[5] + acc[4] + acc[3] + acc[2] + acc[1] + acc[0];
        means[0 * N_NEU + n] = s1;
        means[1 * N_NEU + n] = s2 * 0.5f;
        means[2 * N_NEU + n] = s4 * 0.25f;
        means[3 * N_NEU + n] = s8 * 0.125f;
        means[4 * N_NEU + n] = s16 * 0.0625f;
        return;
    }

    // ---- block 16: attention chain entirely in LDS ----
    for (int idx = tid; idx < 32 * 128; idx += 256) {
        int t = idx >> 7, d = idx & 127;
        sm.attn.xs[t][d] = x[(size_t)(T_TOK - 32 + t) * D_DIM + d];
    }
    __syncthreads();

    const int d = tid & 127;
    const int g = tid >> 7;   // row group {0,1}: rows g*16 .. g*16+15
    float vacc[16];
    {
        float acc[16];
        float bias = bq[d];
#pragma unroll
        for (int i = 0; i < 16; ++i) acc[i] = bias;
#pragma unroll 4
        for (int e = 0; e < 128; ++e) {
            float w = Wq[e * 128 + d];
#pragma unroll
            for (int i = 0; i < 16; ++i) acc[i] += sm.attn.xs[g * 16 + i][e] * w;
        }
#pragma unroll
        for (int i = 0; i < 16; ++i) sm.attn.qs[g * 16 + i][d] = acc[i];
        bias = bk[d];
#pragma unroll
        for (int i = 0; i < 16; ++i) acc[i] = bias;
#pragma unroll 4
        for (int e = 0; e < 128; ++e) {
            float w = Wk[e * 128 + d];
#pragma unroll
            for (int i = 0; i < 16; ++i) acc[i] += sm.attn.xs[g * 16 + i][e] * w;
        }
#pragma unroll
        for (int i = 0; i < 16; ++i) sm.attn.kt[d][g * 16 + i] = acc[i];
        bias = bv[d];
#pragma unroll
        for (int i = 0; i < 16; ++i) vacc[i] = bias;
#pragma unroll 4
        for (int e = 0; e < 128; ++e) {
            float w = Wv[e * 128 + d];
#pragma unroll
            for (int i = 0; i < 16; ++i) vacc[i] += sm.attn.xs[g * 16 + i][e] * w;
        }
    }
    __syncthreads();
#pragma unroll
    for (int i = 0; i < 16; ++i) sm.attn.xs[g * 16 + i][d] = vacc[i];  // xs := v
    __syncthreads();

    const float scale = 0.08838834764831845f;  // 1/sqrt(128)
#pragma unroll
    for (int rep = 0; rep < 4; ++rep) {
        int idx = tid + rep * 256;
        int i = idx >> 5, j = idx & 31;
        float acc = 0.f;
        for (int e = 0; e < 128; ++e) acc += sm.attn.qs[i][e] * sm.attn.kt[e][j];
        sm.attn.ps[i][j] = acc * scale;
    }
    __syncthreads();
    if (tid < 32) {    // softmax over row tid
        float mx = -1e30f;
        for (int j = 0; j < 32; ++j) mx = fmaxf(mx, sm.attn.ps[tid][j]);
        float s = 0.f;
        for (int j = 0; j < 32; ++j) { float e = expf(sm.attn.ps[tid][j] - mx); sm.attn.ps[tid][j] = e; s += e; }
        float inv = 1.f / s;
        for (int j = 0; j < 32; ++j) sm.attn.ps[tid][j] *= inv;
    }
    __syncthreads();
    if (tid < 32) {    // mean over queries of column tid
        float s = 0.f;
        for (int i = 0; i < 32; ++i) s += sm.attn.ps[i][tid];
        sm.attn.pbar[tid] = s * (1.f / 32.f);
    }
    __syncthreads();
    if (tid < 128) {   // attended mean[d] = sum_j pbar[j] * v[j][d]
        float s = 0.f;
        for (int j = 0; j < 32; ++j) s += sm.attn.pbar[j] * sm.attn.xs[j][tid];
        sm.attn.mvec[tid] = s;
    }
    __syncthreads();
    if (tid < 64) {    // mean
        float p = sm.attn.mvec[tid] + sm.attn.mvec[tid + 64];
        for (int off = 32; off; off >>= 1) p += __shfl_down(p, off);
        if (tid == 0) sm.attn.red[0] = p * (1.f / 128.f);
    }
    __syncthreads();
    float mu = sm.attn.red[0];
    if (tid < 64) {    // variance
        float t1 = sm.attn.mvec[tid] - mu, t2 = sm.attn.mvec[tid + 64] - mu;
        float p = t1 * t1 + t2 * t2;
        for (int off = 32; off; off >>= 1) p += __shfl_down(p, off);
        if (tid == 0) sm.attn.red[1] = rsqrtf(p * (1.f / 128.f) + 1e-5f);
    }
    __syncthreads();
    if (tid < 128) {
        yvec[tid] = (sm.attn.mvec[tid] - mu) * sm.attn.red[1] * ln_g[tid] + ln_b[tid];
    }
}

// ---------------------------------------------------------------------------
// Kernel 2: combo partials. 256 blocks x 1024 threads, one block per CU.
// Block = chunk of 96 rows x ALL 4096 cols: the 16 waves cover one full
// 16 KB row per iteration (tid*16B), rows sequential -> each block streams a
// fully CONTIGUOUS 1.5 MB of comboW. v computed inline per row (seg 5 rows
// inline the tiny proj: yvec . projW[:,m] + projb[m]).
// ---------------------------------------------------------------------------
__global__ __launch_bounds__(1024) void combo_partial_kernel(
    const float* __restrict__ means,   // [5][4096]
    const float* __restrict__ ww,      // [6]
    const float* __restrict__ yvec,    // [128]
    const float* __restrict__ projW,   // [128][4096]
    const float* __restrict__ projb,   // [4096]
    const float* __restrict__ comboW,  // [24576][4096]
    float* __restrict__ part)          // [NCHUNK][4096]
{
    __shared__ float vsm[RPC];
    __shared__ float ys[128];
    const int tid = threadIdx.x;
    const int chunk = blockIdx.x;
    const int row0 = chunk * RPC;

    if (tid < 128) ys[tid] = yvec[tid];
    float denom = 0.1f;
#pragma unroll
    for (int i = 0; i < 6; ++i) denom += ww[i];
    __syncthreads();

    if (tid < RPC) {
        int r = row0 + tid;
        int seg = r >> 12;           // 96 doesn't align to 4096: per-element seg
        int m = r & 4095;
        float nw = (ww[seg] + 0.1f) / denom;
        float val;
        if (seg < 5) {
            val = means[seg * N_NEU + m];
        } else {
            float acc = projb[m];
#pragma unroll 4
            for (int e = 0; e < 128; ++e) acc += ys[e] * projW[e * N_NEU + m];
            val = acc;
        }
        vsm[tid] = val * nw;
    }
    __syncthreads();

    const float4* W4 = reinterpret_cast<const float4*>(comboW);
    const size_t base = (size_t)row0 * 1024 + tid;   // float4 index
    float4 acc = make_float4(0.f, 0.f, 0.f, 0.f);
#pragma unroll 8
    for (int r = 0; r < RPC; ++r) {
        float v = vsm[r];                            // LDS broadcast
        float4 w = W4[base + (size_t)r * 1024];      // wave: 1 KB contiguous
        acc.x += v * w.x; acc.y += v * w.y; acc.z += v * w.z; acc.w += v * w.w;
    }
    reinterpret_cast<float4*>(part)[(size_t)chunk * 1024 + tid] = acc;
}

// ---------------------------------------------------------------------------
// Kernel 3: reduce partials + bias. 32 blocks x 256; two thread-halves split
// the 256 chunks (128-deep chains), LDS combine.
// ---------------------------------------------------------------------------
__global__ void combo_reduce_kernel(const float* __restrict__ part,
                                    const float* __restrict__ bias,
                                    float* __restrict__ out)
{
    __shared__ float red[128];
    const int tid = threadIdx.x;
    const int n = blockIdx.x * 128 + (tid & 127);
    const int h = tid >> 7;                   // 0 or 1
    float acc = 0.f;
#pragma unroll 8
    for (int c = h * 128; c < h * 128 + 128; ++c)
        acc += part[(size_t)c * N_NEU + n];
    if (h == 1) red[tid - 128] = acc;
    __syncthreads();
    if (h == 0) out[n] = acc + red[tid] + bias[n];
}

// ---------------------------------------------------------------------------
extern "C" void kernel_launch(void* const* d_in, const int* in_sizes, int n_in,
                              void* d_out, int out_size, void* d_ws, size_t ws_size,
                              hipStream_t stream) {
    const float* inputEmbeds = (const float*)d_in[0];
    const float* neuronW     = (const float*)d_in[1];
    const float* neuronB     = (const float*)d_in[2];
    const float* Wq          = (const float*)d_in[3];
    const float* bq          = (const float*)d_in[4];
    const float* Wk          = (const float*)d_in[5];
    const float* bk          = (const float*)d_in[6];
    const float* Wv          = (const float*)d_in[7];
    const float* bv          = (const float*)d_in[8];
    const float* ln_g        = (const float*)d_in[9];
    const float* ln_b        = (const float*)d_in[10];
    const float* projW       = (const float*)d_in[11];
    const float* projb       = (const float*)d_in[12];
    const float* ww          = (const float*)d_in[13];
    const float* comboW      = (const float*)d_in[14];
    const float* combob      = (const float*)d_in[15];
    float* out = (float*)d_out;
    float* ws  = (float*)d_ws;

    float* means = ws;            // 5*4096 = 20480
    float* yvec  = ws + 20480;    // 128
    float* part  = ws + 20608;    // NCHUNK*4096

    means_attn_kernel<<<17, 256, 0, stream>>>(inputEmbeds, neuronW, neuronB,
                                              Wq, bq, Wk, bk, Wv, bv,
                                              ln_g, ln_b, means, yvec);
    combo_partial_kernel<<<NCHUNK, 1024, 0, stream>>>(means, ww, yvec,
                                                      projW, projb, comboW, part);
    combo_reduce_kernel<<<32, 256, 0, stream>>>(part, combob, out);
}

// Round 6
// 142.146 us; speedup vs baseline: 1.1490x; 1.1490x over previous
//
#include <hip/hip_runtime.h>

#define T_TOK 8192
#define D_DIM 128
#define N_NEU 4096
#define RPC 96             // rows per chunk in combo phase
#define NCHUNK 256         // 24576 / RPC -> one block per CU

typedef float f4_t __attribute__((ext_vector_type(4)));

// ---------------------------------------------------------------------------
// Kernel 1: blocks 0..15  -> acts (last 16 tokens) + window means w=1,2,4,8,16
//           block 16      -> qkv -> 32x32 attention -> mean -> LayerNorm -> yvec
// This round: ALL weight reads go through LDS staging (coalesced float4
// bursts, independent loads) instead of serial per-iteration column loads.
// ---------------------------------------------------------------------------
struct SmemActs {
    float xs16[16][128];   // 8 KB
    float wst[32][256];    // 32 KB  staged neuronW chunk [32 rows][256 cols]
};
struct SmemAttn {
    float xs[32][128];     // 16 KB  last-32 tokens; later overwritten with v
    float qs[32][128];     // 16 KB
    float kt[128][33];     // 16.5 KB k transposed, padded
    float wstage[32][128]; // 16 KB  staged Wq/Wk/Wv chunk (32 rows)
    float ps[32][33];      // 4.2 KB
    float pbar[32];
    float mvec[128];
    float red[2];
};
union Smem1 {
    SmemActs a;
    SmemAttn b;
};

__global__ void means_attn_kernel(
    const float* __restrict__ x,
    const float* __restrict__ neuronW, const float* __restrict__ neuronB,
    const float* __restrict__ Wq, const float* __restrict__ bq,
    const float* __restrict__ Wk, const float* __restrict__ bk,
    const float* __restrict__ Wv, const float* __restrict__ bv,
    const float* __restrict__ ln_g, const float* __restrict__ ln_b,
    float* __restrict__ means,   // [5][4096]
    float* __restrict__ yvec)    // [128]
{
    __shared__ Smem1 sm;
    const int tid = threadIdx.x;
    const int bid = blockIdx.x;

    if (bid < 16) {
        const int n0 = bid * 256;
        const int n = n0 + tid;
        for (int idx = tid; idx < 16 * 128; idx += 256) {
            int t = idx >> 7, d = idx & 127;
            sm.a.xs16[t][d] = x[(size_t)(T_TOK - 16 + t) * D_DIM + d];
        }
        float acc[16];
        float bias = neuronB[n];
#pragma unroll
        for (int t = 0; t < 16; ++t) acc[t] = bias;
        const f4_t* W4 = reinterpret_cast<const f4_t*>(neuronW);
        f4_t* wst4 = reinterpret_cast<f4_t*>(&sm.a.wst[0][0]);
        for (int c = 0; c < 4; ++c) {
            const int d0 = c * 32;
            __syncthreads();   // wst free from previous compute (also covers xs16 at c=0)
#pragma unroll
            for (int k = 0; k < 8; ++k) {
                int idx = tid + k * 256;         // 0..2047 float4
                int dd = idx >> 6, j4 = idx & 63;
                wst4[dd * 64 + j4] = W4[(size_t)(d0 + dd) * 1024 + (n0 >> 2) + j4];
            }
            __syncthreads();
#pragma unroll
            for (int dd = 0; dd < 32; ++dd) {
                float w = sm.a.wst[dd][tid];     // conflict-free (2 lanes/bank)
#pragma unroll
                for (int t = 0; t < 16; ++t) acc[t] += sm.a.xs16[t][d0 + dd] * w;
            }
        }
#pragma unroll
        for (int t = 0; t < 16; ++t) acc[t] = tanhf(acc[t]);  // |tanh|<=1 => clip no-op
        float s1 = acc[15];
        float s2 = s1 + acc[14];
        float s4 = s2 + acc[13] + acc[12];
        float s8 = s4 + acc[11] + acc[10] + acc[9] + acc[8];
        float s16 = s8 + acc[7] + acc[6] + acc[5] + acc[4] + acc[3] + acc[2] + acc[1] + acc[0];
        means[0 * N_NEU + n] = s1;
        means[1 * N_NEU + n] = s2 * 0.5f;
        means[2 * N_NEU + n] = s4 * 0.25f;
        means[3 * N_NEU + n] = s8 * 0.125f;
        means[4 * N_NEU + n] = s16 * 0.0625f;
        return;
    }

    // ---- block 16: attention chain entirely in LDS, staged weights ----
    for (int idx = tid; idx < 32 * 128; idx += 256) {
        int t = idx >> 7, d = idx & 127;
        sm.b.xs[t][d] = x[(size_t)(T_TOK - 32 + t) * D_DIM + d];
    }

    const int d = tid & 127;
    const int g = tid >> 7;   // row group {0,1}: rows g*16 .. g*16+15
    float vacc[16];
    f4_t* ws4 = reinterpret_cast<f4_t*>(&sm.b.wstage[0][0]);
    for (int m = 0; m < 3; ++m) {
        const float* Wm = (m == 0) ? Wq : ((m == 1) ? Wk : Wv);
        const float* bb = (m == 0) ? bq : ((m == 1) ? bk : bv);
        const f4_t* Wm4 = reinterpret_cast<const f4_t*>(Wm);
        float acc[16];
        float bias = bb[d];
#pragma unroll
        for (int i = 0; i < 16; ++i) acc[i] = bias;
        for (int c = 0; c < 4; ++c) {    // 32-row chunks of Wm
            __syncthreads();   // wstage free (and xs staged at first iteration)
#pragma unroll
            for (int k = 0; k < 4; ++k) {
                int idx = tid + k * 256;         // 0..1023 float4 (32 rows x 32 f4)
                int ee = idx >> 5, j4 = idx & 31;
                ws4[ee * 32 + j4] = Wm4[(size_t)(c * 32 + ee) * 32 + j4];
            }
            __syncthreads();
#pragma unroll
            for (int el = 0; el < 32; ++el) {
                float w = sm.b.wstage[el][d];
#pragma unroll
                for (int i = 0; i < 16; ++i) acc[i] += sm.b.xs[g * 16 + i][c * 32 + el] * w;
            }
        }
        if (m == 0) {
#pragma unroll
            for (int i = 0; i < 16; ++i) sm.b.qs[g * 16 + i][d] = acc[i];
        } else if (m == 1) {
#pragma unroll
            for (int i = 0; i < 16; ++i) sm.b.kt[d][g * 16 + i] = acc[i];
        } else {
#pragma unroll
            for (int i = 0; i < 16; ++i) vacc[i] = acc[i];
        }
    }
    __syncthreads();
#pragma unroll
    for (int i = 0; i < 16; ++i) sm.b.xs[g * 16 + i][d] = vacc[i];  // xs := v
    __syncthreads();

    const float scale = 0.08838834764831845f;  // 1/sqrt(128)
#pragma unroll
    for (int rep = 0; rep < 4; ++rep) {
        int idx = tid + rep * 256;
        int i = idx >> 5, j = idx & 31;
        float acc = 0.f;
        for (int e = 0; e < 128; ++e) acc += sm.b.qs[i][e] * sm.b.kt[e][j];
        sm.b.ps[i][j] = acc * scale;
    }
    __syncthreads();
    if (tid < 32) {    // softmax over row tid
        float mx = -1e30f;
        for (int j = 0; j < 32; ++j) mx = fmaxf(mx, sm.b.ps[tid][j]);
        float s = 0.f;
        for (int j = 0; j < 32; ++j) { float e = expf(sm.b.ps[tid][j] - mx); sm.b.ps[tid][j] = e; s += e; }
        float inv = 1.f / s;
        for (int j = 0; j < 32; ++j) sm.b.ps[tid][j] *= inv;
    }
    __syncthreads();
    if (tid < 32) {    // mean over queries of column tid
        float s = 0.f;
        for (int i = 0; i < 32; ++i) s += sm.b.ps[i][tid];
        sm.b.pbar[tid] = s * (1.f / 32.f);
    }
    __syncthreads();
    if (tid < 128) {   // attended mean[d] = sum_j pbar[j] * v[j][d]
        float s = 0.f;
        for (int j = 0; j < 32; ++j) s += sm.b.pbar[j] * sm.b.xs[j][tid];
        sm.b.mvec[tid] = s;
    }
    __syncthreads();
    if (tid < 64) {    // mean
        float p = sm.b.mvec[tid] + sm.b.mvec[tid + 64];
        for (int off = 32; off; off >>= 1) p += __shfl_down(p, off);
        if (tid == 0) sm.b.red[0] = p * (1.f / 128.f);
    }
    __syncthreads();
    float mu = sm.b.red[0];
    if (tid < 64) {    // variance
        float t1 = sm.b.mvec[tid] - mu, t2 = sm.b.mvec[tid + 64] - mu;
        float p = t1 * t1 + t2 * t2;
        for (int off = 32; off; off >>= 1) p += __shfl_down(p, off);
        if (tid == 0) sm.b.red[1] = rsqrtf(p * (1.f / 128.f) + 1e-5f);
    }
    __syncthreads();
    if (tid < 128) {
        yvec[tid] = (sm.b.mvec[tid] - mu) * sm.b.red[1] * ln_g[tid] + ln_b[tid];
    }
}

// ---------------------------------------------------------------------------
// Kernel 2: combo partials. 256 blocks x 1024 threads, one block per CU;
// each block streams a contiguous 1.5 MB of comboW (16 waves = one 16 KB row
// per iteration). comboW loads are NONTEMPORAL (bypass L2/L3 allocation --
// the 402 MB stream thrashes L3 anyway; experiment of this round).
// seg-5 rows inline the tiny proj (yvec . projW[:,m] + projb[m]).
// ---------------------------------------------------------------------------
__global__ __launch_bounds__(1024) void combo_partial_kernel(
    const float* __restrict__ means,   // [5][4096]
    const float* __restrict__ ww,      // [6]
    const float* __restrict__ yvec,    // [128]
    const float* __restrict__ projW,   // [128][4096]
    const float* __restrict__ projb,   // [4096]
    const float* __restrict__ comboW,  // [24576][4096]
    float* __restrict__ part)          // [NCHUNK][4096]
{
    __shared__ float vsm[RPC];
    __shared__ float ys[128];
    const int tid = threadIdx.x;
    const int chunk = blockIdx.x;
    const int row0 = chunk * RPC;

    if (tid < 128) ys[tid] = yvec[tid];
    float denom = 0.1f;
#pragma unroll
    for (int i = 0; i < 6; ++i) denom += ww[i];
    __syncthreads();

    if (tid < RPC) {
        int r = row0 + tid;
        int seg = r >> 12;           // 96 doesn't align to 4096: per-element seg
        int m = r & 4095;
        float nw = (ww[seg] + 0.1f) / denom;
        float val;
        if (seg < 5) {
            val = means[seg * N_NEU + m];
        } else {
            float acc = projb[m];
#pragma unroll 4
            for (int e = 0; e < 128; ++e) acc += ys[e] * projW[e * N_NEU + m];
            val = acc;
        }
        vsm[tid] = val * nw;
    }
    __syncthreads();

    const f4_t* W4 = reinterpret_cast<const f4_t*>(comboW);
    const size_t base = (size_t)row0 * 1024 + tid;   // float4 index
    f4_t acc = {0.f, 0.f, 0.f, 0.f};
#pragma unroll 8
    for (int r = 0; r < RPC; ++r) {
        float v = vsm[r];                                        // LDS broadcast
        f4_t w = __builtin_nontemporal_load(&W4[base + (size_t)r * 1024]);
        acc += w * v;
    }
    reinterpret_cast<f4_t*>(part)[(size_t)chunk * 1024 + tid] = acc;
}

// ---------------------------------------------------------------------------
// Kernel 3: reduce partials + bias. 16 blocks x 256 threads, float4 cols,
// 4-way chunk split (64-deep chains) + LDS combine.
// ---------------------------------------------------------------------------
__global__ void combo_reduce_kernel(const float* __restrict__ part,
                                    const float* __restrict__ bias,
                                    float* __restrict__ out)
{
    __shared__ f4_t red[4][64];
    const int tid = threadIdx.x;
    const int h = tid >> 6;                 // 0..3: chunk quarter
    const int j = tid & 63;
    const int n4 = blockIdx.x * 64 + j;     // 16 blocks x 64 f4 = 1024 f4 = 4096 cols
    const f4_t* P4 = reinterpret_cast<const f4_t*>(part);
    f4_t acc = {0.f, 0.f, 0.f, 0.f};
#pragma unroll 8
    for (int c = h * 64; c < h * 64 + 64; ++c)
        acc += P4[(size_t)c * 1024 + n4];
    red[h][j] = acc;
    __syncthreads();
    if (h == 0) {
        f4_t s = red[0][j] + red[1][j] + red[2][j] + red[3][j];
        s += reinterpret_cast<const f4_t*>(bias)[n4];
        reinterpret_cast<f4_t*>(out)[n4] = s;
    }
}

// ---------------------------------------------------------------------------
extern "C" void kernel_launch(void* const* d_in, const int* in_sizes, int n_in,
                              void* d_out, int out_size, void* d_ws, size_t ws_size,
                              hipStream_t stream) {
    const float* inputEmbeds = (const float*)d_in[0];
    const float* neuronW     = (const float*)d_in[1];
    const float* neuronB     = (const float*)d_in[2];
    const float* Wq          = (const float*)d_in[3];
    const float* bq          = (const float*)d_in[4];
    const float* Wk          = (const float*)d_in[5];
    const float* bk          = (const float*)d_in[6];
    const float* Wv          = (const float*)d_in[7];
    const float* bv          = (const float*)d_in[8];
    const float* ln_g        = (const float*)d_in[9];
    const float* ln_b        = (const float*)d_in[10];
    const float* projW       = (const float*)d_in[11];
    const float* projb       = (const float*)d_in[12];
    const float* ww          = (const float*)d_in[13];
    const float* comboW      = (const float*)d_in[14];
    const float* combob      = (const float*)d_in[15];
    float* out = (float*)d_out;
    float* ws  = (float*)d_ws;

    float* means = ws;            // 5*4096 = 20480
    float* yvec  = ws + 20480;    // 128
    float* part  = ws + 20608;    // NCHUNK*4096

    means_attn_kernel<<<17, 256, 0, stream>>>(inputEmbeds, neuronW, neuronB,
                                              Wq, bq, Wk, bk, Wv, bv,
                                              ln_g, ln_b, means, yvec);
    combo_partial_kernel<<<NCHUNK, 1024, 0, stream>>>(means, ww, yvec,
                                                      projW, projb, comboW, part);
    combo_reduce_kernel<<<16, 256, 0, stream>>>(part, combob, out);
}

// Round 7
// 131.048 us; speedup vs baseline: 1.2463x; 1.0847x over previous
//
#include <hip/hip_runtime.h>

#define T_TOK 8192
#define D_DIM 128
#define N_NEU 4096
#define RPC 96             // rows per chunk in combo phase
#define NCHUNK 256         // 24576 / RPC -> one block per CU

typedef float f4_t __attribute__((ext_vector_type(4)));

// ---------------------------------------------------------------------------
// Kernel A: blocks 0..15  -> acts (last 16 tokens) + window means w=1,2,4,8,16
//           blocks 16..18 -> q/k/v projection (one matrix per block), full
//                            64 KB weight staged to LDS in ONE burst.
// ---------------------------------------------------------------------------
struct SmemActs {
    float xs16[16][128];   // 8 KB
    float wst[32][256];    // 32 KB staged neuronW chunk
};
struct SmemQkv {
    float xs[32][128];     // 16 KB last-32 tokens
    float w[128][128];     // 64 KB full weight matrix
};
union SmemA {
    SmemActs a;
    SmemQkv q;
};

__global__ void acts_qkv_kernel(
    const float* __restrict__ x,
    const float* __restrict__ neuronW, const float* __restrict__ neuronB,
    const float* __restrict__ Wq, const float* __restrict__ bq,
    const float* __restrict__ Wk, const float* __restrict__ bk,
    const float* __restrict__ Wv, const float* __restrict__ bv,
    float* __restrict__ means,   // [5][4096]
    float* __restrict__ qkv)     // [3][32][128]
{
    __shared__ SmemA sm;
    const int tid = threadIdx.x;
    const int bid = blockIdx.x;

    if (bid < 16) {
        // ---- acts + window means (verified rounds 3-6) ----
        const int n0 = bid * 256;
        const int n = n0 + tid;
        for (int idx = tid; idx < 16 * 128; idx += 256) {
            int t = idx >> 7, d = idx & 127;
            sm.a.xs16[t][d] = x[(size_t)(T_TOK - 16 + t) * D_DIM + d];
        }
        float acc[16];
        float bias = neuronB[n];
#pragma unroll
        for (int t = 0; t < 16; ++t) acc[t] = bias;
        const f4_t* W4 = reinterpret_cast<const f4_t*>(neuronW);
        f4_t* wst4 = reinterpret_cast<f4_t*>(&sm.a.wst[0][0]);
        for (int c = 0; c < 4; ++c) {
            const int d0 = c * 32;
            __syncthreads();   // wst free (also covers xs16 at c=0)
#pragma unroll
            for (int k = 0; k < 8; ++k) {
                int idx = tid + k * 256;         // 0..2047 float4
                int dd = idx >> 6, j4 = idx & 63;
                wst4[dd * 64 + j4] = W4[(size_t)(d0 + dd) * 1024 + (n0 >> 2) + j4];
            }
            __syncthreads();
#pragma unroll
            for (int dd = 0; dd < 32; ++dd) {
                float w = sm.a.wst[dd][tid];     // conflict-free
#pragma unroll
                for (int t = 0; t < 16; ++t) acc[t] += sm.a.xs16[t][d0 + dd] * w;
            }
        }
#pragma unroll
        for (int t = 0; t < 16; ++t) acc[t] = tanhf(acc[t]);  // |tanh|<=1 => clip no-op
        float s1 = acc[15];
        float s2 = s1 + acc[14];
        float s4 = s2 + acc[13] + acc[12];
        float s8 = s4 + acc[11] + acc[10] + acc[9] + acc[8];
        float s16 = s8 + acc[7] + acc[6] + acc[5] + acc[4] + acc[3] + acc[2] + acc[1] + acc[0];
        means[0 * N_NEU + n] = s1;
        means[1 * N_NEU + n] = s2 * 0.5f;
        means[2 * N_NEU + n] = s4 * 0.25f;
        means[3 * N_NEU + n] = s8 * 0.125f;
        means[4 * N_NEU + n] = s16 * 0.0625f;
        return;
    }

    // ---- blocks 16..18: one q/k/v matrix each, full-W single-burst staging --
    const int m = bid - 16;
    const float* Wm = (m == 0) ? Wq : ((m == 1) ? Wk : Wv);
    const float* bb = (m == 0) ? bq : ((m == 1) ? bk : bv);

    f4_t* xs4 = reinterpret_cast<f4_t*>(&sm.q.xs[0][0]);
    const f4_t* X4 = reinterpret_cast<const f4_t*>(x + (size_t)(T_TOK - 32) * D_DIM);
#pragma unroll
    for (int k = 0; k < 4; ++k) xs4[tid + k * 256] = X4[tid + k * 256];
    f4_t* w4 = reinterpret_cast<f4_t*>(&sm.q.w[0][0]);
    const f4_t* Wm4 = reinterpret_cast<const f4_t*>(Wm);
#pragma unroll
    for (int k = 0; k < 16; ++k) w4[tid + k * 256] = Wm4[tid + k * 256];   // 20 indep loads in flight
    __syncthreads();

    const int d = tid & 127;
    const int g = tid >> 7;   // rows g*16 .. g*16+15
    float acc[16];
    float bias = bb[d];
#pragma unroll
    for (int i = 0; i < 16; ++i) acc[i] = bias;
#pragma unroll 4
    for (int e = 0; e < 128; ++e) {
        float w = sm.q.w[e][d];
#pragma unroll
        for (int i = 0; i < 16; ++i) acc[i] += sm.q.xs[g * 16 + i][e] * w;
    }
#pragma unroll
    for (int i = 0; i < 16; ++i) qkv[m * 4096 + (g * 16 + i) * 128 + d] = acc[i];
}

// ---------------------------------------------------------------------------
// Kernel B: 32x32 attention + query-mean + LayerNorm (1 block x 256).
// q/k/v read from ws (L2-hot). Verified structure from round 3.
// ---------------------------------------------------------------------------
struct SmemAttn {
    float qs[32][128];
    float kt[128][33];   // k transposed, padded
    float vs[32][128];
    float ps[32][33];
    float pbar[32];
    float mvec[128];
    float red[2];
};

__global__ void attn_kernel(const float* __restrict__ qkv,
                            const float* __restrict__ ln_g, const float* __restrict__ ln_b,
                            float* __restrict__ yvec)   // [128]
{
    __shared__ SmemAttn sm;
    const int tid = threadIdx.x;
    for (int idx = tid; idx < 32 * 128; idx += 256) {
        int i = idx >> 7, d = idx & 127;
        sm.qs[i][d] = qkv[idx];
        sm.kt[d][i] = qkv[4096 + idx];
        sm.vs[i][d] = qkv[8192 + idx];
    }
    __syncthreads();
    const float scale = 0.08838834764831845f;  // 1/sqrt(128)
#pragma unroll
    for (int rep = 0; rep < 4; ++rep) {
        int idx = tid + rep * 256;
        int i = idx >> 5, j = idx & 31;
        float acc = 0.f;
        for (int e = 0; e < 128; ++e) acc += sm.qs[i][e] * sm.kt[e][j];
        sm.ps[i][j] = acc * scale;
    }
    __syncthreads();
    if (tid < 32) {    // softmax over row tid
        float mx = -1e30f;
        for (int j = 0; j < 32; ++j) mx = fmaxf(mx, sm.ps[tid][j]);
        float s = 0.f;
        for (int j = 0; j < 32; ++j) { float e = expf(sm.ps[tid][j] - mx); sm.ps[tid][j] = e; s += e; }
        float inv = 1.f / s;
        for (int j = 0; j < 32; ++j) sm.ps[tid][j] *= inv;
    }
    __syncthreads();
    if (tid < 32) {    // mean over queries of column tid
        float s = 0.f;
        for (int i = 0; i < 32; ++i) s += sm.ps[i][tid];
        sm.pbar[tid] = s * (1.f / 32.f);
    }
    __syncthreads();
    if (tid < 128) {   // attended mean[d]
        float s = 0.f;
        for (int j = 0; j < 32; ++j) s += sm.pbar[j] * sm.vs[j][tid];
        sm.mvec[tid] = s;
    }
    __syncthreads();
    if (tid < 64) {    // mean
        float p = sm.mvec[tid] + sm.mvec[tid + 64];
        for (int off = 32; off; off >>= 1) p += __shfl_down(p, off);
        if (tid == 0) sm.red[0] = p * (1.f / 128.f);
    }
    __syncthreads();
    float mu = sm.red[0];
    if (tid < 64) {    // variance
        float t1 = sm.mvec[tid] - mu, t2 = sm.mvec[tid + 64] - mu;
        float p = t1 * t1 + t2 * t2;
        for (int off = 32; off; off >>= 1) p += __shfl_down(p, off);
        if (tid == 0) sm.red[1] = rsqrtf(p * (1.f / 128.f) + 1e-5f);
    }
    __syncthreads();
    if (tid < 128) {
        yvec[tid] = (sm.mvec[tid] - mu) * sm.red[1] * ln_g[tid] + ln_b[tid];
    }
}

// ---------------------------------------------------------------------------
// Kernel C: combo partials. 256 blocks x 1024 threads; each block streams a
// contiguous 1.5 MB of comboW. PLAIN loads this round (nt forfeited the ~50%
// L3 hit rate observed in round 3's FETCH_SIZE). seg-5 rows inline the proj.
// ---------------------------------------------------------------------------
__global__ __launch_bounds__(1024) void combo_partial_kernel(
    const float* __restrict__ means,   // [5][4096]
    const float* __restrict__ ww,      // [6]
    const float* __restrict__ yvec,    // [128]
    const float* __restrict__ projW,   // [128][4096]
    const float* __restrict__ projb,   // [4096]
    const float* __restrict__ comboW,  // [24576][4096]
    float* __restrict__ part)          // [NCHUNK][4096]
{
    __shared__ float vsm[RPC];
    __shared__ float ys[128];
    const int tid = threadIdx.x;
    const int chunk = blockIdx.x;
    const int row0 = chunk * RPC;

    if (tid < 128) ys[tid] = yvec[tid];
    float denom = 0.1f;
#pragma unroll
    for (int i = 0; i < 6; ++i) denom += ww[i];
    __syncthreads();

    if (tid < RPC) {
        int r = row0 + tid;
        int seg = r >> 12;           // per-element seg (96 not aligned to 4096)
        int m = r & 4095;
        float nw = (ww[seg] + 0.1f) / denom;
        float val;
        if (seg < 5) {
            val = means[seg * N_NEU + m];
        } else {
            float acc = projb[m];
#pragma unroll 4
            for (int e = 0; e < 128; ++e) acc += ys[e] * projW[e * N_NEU + m];
            val = acc;
        }
        vsm[tid] = val * nw;
    }
    __syncthreads();

    const f4_t* W4 = reinterpret_cast<const f4_t*>(comboW);
    const size_t base = (size_t)row0 * 1024 + tid;   // float4 index
    f4_t acc = {0.f, 0.f, 0.f, 0.f};
#pragma unroll 8
    for (int r = 0; r < RPC; ++r) {
        float v = vsm[r];                            // LDS broadcast
        f4_t w = W4[base + (size_t)r * 1024];        // wave: 1 KB contiguous
        acc += w * v;
    }
    reinterpret_cast<f4_t*>(part)[(size_t)chunk * 1024 + tid] = acc;
}

// ---------------------------------------------------------------------------
// Kernel D: reduce partials + bias. 16 blocks x 256 threads, float4 cols,
// 4-way chunk split + LDS combine.
// ---------------------------------------------------------------------------
__global__ void combo_reduce_kernel(const float* __restrict__ part,
                                    const float* __restrict__ bias,
                                    float* __restrict__ out)
{
    __shared__ f4_t red[4][64];
    const int tid = threadIdx.x;
    const int h = tid >> 6;                 // 0..3: chunk quarter
    const int j = tid & 63;
    const int n4 = blockIdx.x * 64 + j;
    const f4_t* P4 = reinterpret_cast<const f4_t*>(part);
    f4_t acc = {0.f, 0.f, 0.f, 0.f};
#pragma unroll 8
    for (int c = h * 64; c < h * 64 + 64; ++c)
        acc += P4[(size_t)c * 1024 + n4];
    red[h][j] = acc;
    __syncthreads();
    if (h == 0) {
        f4_t s = red[0][j] + red[1][j] + red[2][j] + red[3][j];
        s += reinterpret_cast<const f4_t*>(bias)[n4];
        reinterpret_cast<f4_t*>(out)[n4] = s;
    }
}

// ---------------------------------------------------------------------------
extern "C" void kernel_launch(void* const* d_in, const int* in_sizes, int n_in,
                              void* d_out, int out_size, void* d_ws, size_t ws_size,
                              hipStream_t stream) {
    const float* inputEmbeds = (const float*)d_in[0];
    const float* neuronW     = (const float*)d_in[1];
    const float* neuronB     = (const float*)d_in[2];
    const float* Wq          = (const float*)d_in[3];
    const float* bq          = (const float*)d_in[4];
    const float* Wk          = (const float*)d_in[5];
    const float* bk          = (const float*)d_in[6];
    const float* Wv          = (const float*)d_in[7];
    const float* bv          = (const float*)d_in[8];
    const float* ln_g        = (const float*)d_in[9];
    const float* ln_b        = (const float*)d_in[10];
    const float* projW       = (const float*)d_in[11];
    const float* projb       = (const float*)d_in[12];
    const float* ww          = (const float*)d_in[13];
    const float* comboW      = (const float*)d_in[14];
    const float* combob      = (const float*)d_in[15];
    float* out = (float*)d_out;
    float* ws  = (float*)d_ws;

    float* means = ws;                          // 5*4096 = 20480
    float* yvec  = ws + 20480;                  // 128
    float* part  = ws + 20608;                  // NCHUNK*4096
    float* qkv   = ws + 20608 + NCHUNK * 4096;  // 3*4096

    acts_qkv_kernel<<<19, 256, 0, stream>>>(inputEmbeds, neuronW, neuronB,
                                            Wq, bq, Wk, bk, Wv, bv, means, qkv);
    attn_kernel<<<1, 256, 0, stream>>>(qkv, ln_g, ln_b, yvec);
    combo_partial_kernel<<<NCHUNK, 1024, 0, stream>>>(means, ww, yvec,
                                                      projW, projb, comboW, part);
    combo_reduce_kernel<<<16, 256, 0, stream>>>(part, combob, out);
}

// Round 8
// 130.937 us; speedup vs baseline: 1.2474x; 1.0009x over previous
//
#include <hip/hip_runtime.h>

#define T_TOK 8192
#define D_DIM 128
#define N_NEU 4096
#define RPC 48             // rows per chunk in combo phase
#define NCHUNK 512         // 24576 / RPC
#define NPART NCHUNK       // partial rows

typedef float f4_t __attribute__((ext_vector_type(4)));

// ---------------------------------------------------------------------------
// Kernel A: blocks 0..15  -> acts (last 16 tokens) + window means w=1,2,4,8,16
//           blocks 16..18 -> q/k/v projection (one matrix per block), full
//                            64 KB weight staged to LDS in ONE burst.
// (verified rounds 6-7)
// ---------------------------------------------------------------------------
struct SmemActs {
    float xs16[16][128];   // 8 KB
    float wst[32][256];    // 32 KB staged neuronW chunk
};
struct SmemQkv {
    float xs[32][128];     // 16 KB last-32 tokens
    float w[128][128];     // 64 KB full weight matrix
};
union SmemA {
    SmemActs a;
    SmemQkv q;
};

__global__ void acts_qkv_kernel(
    const float* __restrict__ x,
    const float* __restrict__ neuronW, const float* __restrict__ neuronB,
    const float* __restrict__ Wq, const float* __restrict__ bq,
    const float* __restrict__ Wk, const float* __restrict__ bk,
    const float* __restrict__ Wv, const float* __restrict__ bv,
    float* __restrict__ means,   // [5][4096]
    float* __restrict__ qkv)     // [3][32][128]
{
    __shared__ SmemA sm;
    const int tid = threadIdx.x;
    const int bid = blockIdx.x;

    if (bid < 16) {
        const int n0 = bid * 256;
        const int n = n0 + tid;
        for (int idx = tid; idx < 16 * 128; idx += 256) {
            int t = idx >> 7, d = idx & 127;
            sm.a.xs16[t][d] = x[(size_t)(T_TOK - 16 + t) * D_DIM + d];
        }
        float acc[16];
        float bias = neuronB[n];
#pragma unroll
        for (int t = 0; t < 16; ++t) acc[t] = bias;
        const f4_t* W4 = reinterpret_cast<const f4_t*>(neuronW);
        f4_t* wst4 = reinterpret_cast<f4_t*>(&sm.a.wst[0][0]);
        for (int c = 0; c < 4; ++c) {
            const int d0 = c * 32;
            __syncthreads();   // wst free (also covers xs16 at c=0)
#pragma unroll
            for (int k = 0; k < 8; ++k) {
                int idx = tid + k * 256;         // 0..2047 float4
                int dd = idx >> 6, j4 = idx & 63;
                wst4[dd * 64 + j4] = W4[(size_t)(d0 + dd) * 1024 + (n0 >> 2) + j4];
            }
            __syncthreads();
#pragma unroll
            for (int dd = 0; dd < 32; ++dd) {
                float w = sm.a.wst[dd][tid];     // conflict-free
#pragma unroll
                for (int t = 0; t < 16; ++t) acc[t] += sm.a.xs16[t][d0 + dd] * w;
            }
        }
#pragma unroll
        for (int t = 0; t < 16; ++t) acc[t] = tanhf(acc[t]);  // |tanh|<=1 => clip no-op
        float s1 = acc[15];
        float s2 = s1 + acc[14];
        float s4 = s2 + acc[13] + acc[12];
        float s8 = s4 + acc[11] + acc[10] + acc[9] + acc[8];
        float s16 = s8 + acc[7] + acc[6] + acc[5] + acc[4] + acc[3] + acc[2] + acc[1] + acc[0];
        means[0 * N_NEU + n] = s1;
        means[1 * N_NEU + n] = s2 * 0.5f;
        means[2 * N_NEU + n] = s4 * 0.25f;
        means[3 * N_NEU + n] = s8 * 0.125f;
        means[4 * N_NEU + n] = s16 * 0.0625f;
        return;
    }

    // ---- blocks 16..18: one q/k/v matrix each, full-W single-burst staging --
    const int m = bid - 16;
    const float* Wm = (m == 0) ? Wq : ((m == 1) ? Wk : Wv);
    const float* bb = (m == 0) ? bq : ((m == 1) ? bk : bv);

    f4_t* xs4 = reinterpret_cast<f4_t*>(&sm.q.xs[0][0]);
    const f4_t* X4 = reinterpret_cast<const f4_t*>(x + (size_t)(T_TOK - 32) * D_DIM);
#pragma unroll
    for (int k = 0; k < 4; ++k) xs4[tid + k * 256] = X4[tid + k * 256];
    f4_t* w4 = reinterpret_cast<f4_t*>(&sm.q.w[0][0]);
    const f4_t* Wm4 = reinterpret_cast<const f4_t*>(Wm);
#pragma unroll
    for (int k = 0; k < 16; ++k) w4[tid + k * 256] = Wm4[tid + k * 256];
    __syncthreads();

    const int d = tid & 127;
    const int g = tid >> 7;
    float acc[16];
    float bias = bb[d];
#pragma unroll
    for (int i = 0; i < 16; ++i) acc[i] = bias;
#pragma unroll 4
    for (int e = 0; e < 128; ++e) {
        float w = sm.q.w[e][d];
#pragma unroll
        for (int i = 0; i < 16; ++i) acc[i] += sm.q.xs[g * 16 + i][e] * w;
    }
#pragma unroll
    for (int i = 0; i < 16; ++i) qkv[m * 4096 + (g * 16 + i) * 128 + d] = acc[i];
}

// ---------------------------------------------------------------------------
// Kernel B: 32x32 attention + query-mean + LayerNorm (1 block x 256).
// (verified rounds 3-7)
// ---------------------------------------------------------------------------
struct SmemAttn {
    float qs[32][128];
    float kt[128][33];
    float vs[32][128];
    float ps[32][33];
    float pbar[32];
    float mvec[128];
    float red[2];
};

__global__ void attn_kernel(const float* __restrict__ qkv,
                            const float* __restrict__ ln_g, const float* __restrict__ ln_b,
                            float* __restrict__ yvec)   // [128]
{
    __shared__ SmemAttn sm;
    const int tid = threadIdx.x;
    for (int idx = tid; idx < 32 * 128; idx += 256) {
        int i = idx >> 7, d = idx & 127;
        sm.qs[i][d] = qkv[idx];
        sm.kt[d][i] = qkv[4096 + idx];
        sm.vs[i][d] = qkv[8192 + idx];
    }
    __syncthreads();
    const float scale = 0.08838834764831845f;  // 1/sqrt(128)
#pragma unroll
    for (int rep = 0; rep < 4; ++rep) {
        int idx = tid + rep * 256;
        int i = idx >> 5, j = idx & 31;
        float acc = 0.f;
        for (int e = 0; e < 128; ++e) acc += sm.qs[i][e] * sm.kt[e][j];
        sm.ps[i][j] = acc * scale;
    }
    __syncthreads();
    if (tid < 32) {
        float mx = -1e30f;
        for (int j = 0; j < 32; ++j) mx = fmaxf(mx, sm.ps[tid][j]);
        float s = 0.f;
        for (int j = 0; j < 32; ++j) { float e = expf(sm.ps[tid][j] - mx); sm.ps[tid][j] = e; s += e; }
        float inv = 1.f / s;
        for (int j = 0; j < 32; ++j) sm.ps[tid][j] *= inv;
    }
    __syncthreads();
    if (tid < 32) {
        float s = 0.f;
        for (int i = 0; i < 32; ++i) s += sm.ps[i][tid];
        sm.pbar[tid] = s * (1.f / 32.f);
    }
    __syncthreads();
    if (tid < 128) {
        float s = 0.f;
        for (int j = 0; j < 32; ++j) s += sm.pbar[j] * sm.vs[j][tid];
        sm.mvec[tid] = s;
    }
    __syncthreads();
    if (tid < 64) {
        float p = sm.mvec[tid] + sm.mvec[tid + 64];
        for (int off = 32; off; off >>= 1) p += __shfl_down(p, off);
        if (tid == 0) sm.red[0] = p * (1.f / 128.f);
    }
    __syncthreads();
    float mu = sm.red[0];
    if (tid < 64) {
        float t1 = sm.mvec[tid] - mu, t2 = sm.mvec[tid + 64] - mu;
        float p = t1 * t1 + t2 * t2;
        for (int off = 32; off; off >>= 1) p += __shfl_down(p, off);
        if (tid == 0) sm.red[1] = rsqrtf(p * (1.f / 128.f) + 1e-5f);
    }
    __syncthreads();
    if (tid < 128) {
        yvec[tid] = (sm.mvec[tid] - mu) * sm.red[1] * ln_g[tid] + ln_b[tid];
    }
}

// ---------------------------------------------------------------------------
// Kernel C: build the full weighted vector v[24576].
// 16 blocks x 256. proj part uses LDS-staged projW (acts staging pattern).
// ---------------------------------------------------------------------------
struct SmemV {
    float ys[128];
    float wst[32][256];
};

__global__ void build_v_kernel(const float* __restrict__ yvec,
                               const float* __restrict__ projW,   // [128][4096]
                               const float* __restrict__ projb,
                               const float* __restrict__ ww,      // [6]
                               const float* __restrict__ means,   // [5][4096]
                               float* __restrict__ v)             // [6][4096]
{
    __shared__ SmemV sm;
    const int tid = threadIdx.x;
    const int n0 = blockIdx.x * 256;
    const int n = n0 + tid;

    if (tid < 128) sm.ys[tid] = yvec[tid];
    float denom = 0.1f;
#pragma unroll
    for (int i = 0; i < 6; ++i) denom += ww[i];
    const float inv = 1.f / denom;

    float acc = projb[n];
    const f4_t* P4 = reinterpret_cast<const f4_t*>(projW);
    f4_t* wst4 = reinterpret_cast<f4_t*>(&sm.wst[0][0]);
    for (int c = 0; c < 4; ++c) {
        const int d0 = c * 32;
        __syncthreads();   // wst free from previous chunk (covers ys at c=0)
#pragma unroll
        for (int k = 0; k < 8; ++k) {
            int idx = tid + k * 256;
            int dd = idx >> 6, j4 = idx & 63;
            wst4[dd * 64 + j4] = P4[(size_t)(d0 + dd) * 1024 + (n0 >> 2) + j4];
        }
        __syncthreads();
#pragma unroll
        for (int dd = 0; dd < 32; ++dd) {
            acc += sm.ys[d0 + dd] * sm.wst[dd][tid];
        }
    }
#pragma unroll
    for (int s = 0; s < 5; ++s)
        v[s * N_NEU + n] = means[s * N_NEU + n] * ((ww[s] + 0.1f) * inv);
    v[5 * N_NEU + n] = acc * ((ww[5] + 0.1f) * inv);
}

// ---------------------------------------------------------------------------
// Kernel D: combo partials — pure stream. 2048 blocks x 256 threads
// (8 blocks/CU, 32 waves/CU). chunk = bid>>2 (48 rows), coltile = bid&3.
// Wave: 64 lanes x float4 = 1 KB contiguous per row iteration.
// ---------------------------------------------------------------------------
__global__ __launch_bounds__(256) void combo_partial_kernel(
    const float* __restrict__ v,       // [24576]
    const float* __restrict__ comboW,  // [24576][4096]
    float* __restrict__ part)          // [NCHUNK][4096]
{
    __shared__ float vsm[RPC];
    const int tid = threadIdx.x;
    const int chunk = blockIdx.x >> 2;
    const int cb = blockIdx.x & 3;
    const int row0 = chunk * RPC;

    if (tid < RPC) vsm[tid] = v[row0 + tid];
    __syncthreads();

    const f4_t* W4 = reinterpret_cast<const f4_t*>(comboW);
    const size_t base = (size_t)row0 * 1024 + cb * 256 + tid;   // float4 index
    f4_t acc = {0.f, 0.f, 0.f, 0.f};
#pragma unroll 8
    for (int r = 0; r < RPC; ++r) {
        acc += W4[base + (size_t)r * 1024] * vsm[r];
    }
    reinterpret_cast<f4_t*>(part)[(size_t)chunk * 1024 + cb * 256 + tid] = acc;
}

// ---------------------------------------------------------------------------
// Kernel E: reduce 512 partials + bias. 16 blocks x 256, f4 cols, 4-way split.
// ---------------------------------------------------------------------------
__global__ void combo_reduce_kernel(const float* __restrict__ part,
                                    const float* __restrict__ bias,
                                    float* __restrict__ out)
{
    __shared__ f4_t red[4][64];
    const int tid = threadIdx.x;
    const int h = tid >> 6;                 // 0..3: chunk quarter (128 each)
    const int j = tid & 63;
    const int n4 = blockIdx.x * 64 + j;
    const f4_t* P4 = reinterpret_cast<const f4_t*>(part);
    f4_t acc = {0.f, 0.f, 0.f, 0.f};
#pragma unroll 8
    for (int c = h * 128; c < h * 128 + 128; ++c)
        acc += P4[(size_t)c * 1024 + n4];
    red[h][j] = acc;
    __syncthreads();
    if (h == 0) {
        f4_t s = red[0][j] + red[1][j] + red[2][j] + red[3][j];
        s += reinterpret_cast<const f4_t*>(bias)[n4];
        reinterpret_cast<f4_t*>(out)[n4] = s;
    }
}

// ---------------------------------------------------------------------------
extern "C" void kernel_launch(void* const* d_in, const int* in_sizes, int n_in,
                              void* d_out, int out_size, void* d_ws, size_t ws_size,
                              hipStream_t stream) {
    const float* inputEmbeds = (const float*)d_in[0];
    const float* neuronW     = (const float*)d_in[1];
    const float* neuronB     = (const float*)d_in[2];
    const float* Wq          = (const float*)d_in[3];
    const float* bq          = (const float*)d_in[4];
    const float* Wk          = (const float*)d_in[5];
    const float* bk          = (const float*)d_in[6];
    const float* Wv          = (const float*)d_in[7];
    const float* bv          = (const float*)d_in[8];
    const float* ln_g        = (const float*)d_in[9];
    const float* ln_b        = (const float*)d_in[10];
    const float* projW       = (const float*)d_in[11];
    const float* projb       = (const float*)d_in[12];
    const float* ww          = (const float*)d_in[13];
    const float* comboW      = (const float*)d_in[14];
    const float* combob      = (const float*)d_in[15];
    float* out = (float*)d_out;
    float* ws  = (float*)d_ws;

    float* means = ws;                      // 5*4096 = 20480
    float* yvec  = ws + 20480;              // 128
    float* qkv   = ws + 20608;              // 3*4096 = 12288
    float* v     = ws + 32896;              // 6*4096 = 24576
    float* part  = ws + 57472;              // NCHUNK*4096

    acts_qkv_kernel<<<19, 256, 0, stream>>>(inputEmbeds, neuronW, neuronB,
                                            Wq, bq, Wk, bk, Wv, bv, means, qkv);
    attn_kernel<<<1, 256, 0, stream>>>(qkv, ln_g, ln_b, yvec);
    build_v_kernel<<<16, 256, 0, stream>>>(yvec, projW, projb, ww, means, v);
    combo_partial_kernel<<<NCHUNK * 4, 256, 0, stream>>>(v, comboW, part);
    combo_reduce_kernel<<<16, 256, 0, stream>>>(part, combob, out);
}

// Round 9
// 109.073 us; speedup vs baseline: 1.4974x; 1.2005x over previous
//
#include <hip/hip_runtime.h>

#define T_TOK 8192
#define D_DIM 128
#define N_NEU 4096
#define RPC 192            // rows per chunk in combo phase
#define NCHUNK 128         // 24576 / RPC

typedef float f4_t __attribute__((ext_vector_type(4)));

// ---------------------------------------------------------------------------
// Kernel A: blocks 0..15  -> acts (last 16 tokens) + window means w=1,2,4,8,16
//                            written DIRECTLY as weighted v rows 0..4.
//           blocks 16..18 -> q/k/v projection (one matrix per block), full
//                            64 KB weight staged to LDS in ONE burst.
// ---------------------------------------------------------------------------
struct SmemActs {
    float xs16[16][128];   // 8 KB
    float wst[32][256];    // 32 KB staged neuronW chunk
};
struct SmemQkv {
    float xs[32][128];     // 16 KB last-32 tokens
    float w[128][128];     // 64 KB full weight matrix
};
union SmemA {
    SmemActs a;
    SmemQkv q;
};

__global__ void acts_qkv_kernel(
    const float* __restrict__ x,
    const float* __restrict__ neuronW, const float* __restrict__ neuronB,
    const float* __restrict__ Wq, const float* __restrict__ bq,
    const float* __restrict__ Wk, const float* __restrict__ bk,
    const float* __restrict__ Wv, const float* __restrict__ bv,
    const float* __restrict__ ww,    // [6]
    float* __restrict__ v,           // [6][4096] weighted vector (rows 0..4 here)
    float* __restrict__ qkv)         // [3][32][128]
{
    __shared__ SmemA sm;
    const int tid = threadIdx.x;
    const int bid = blockIdx.x;

    if (bid < 16) {
        const int n0 = bid * 256;
        const int n = n0 + tid;
        for (int idx = tid; idx < 16 * 128; idx += 256) {
            int t = idx >> 7, d = idx & 127;
            sm.a.xs16[t][d] = x[(size_t)(T_TOK - 16 + t) * D_DIM + d];
        }
        float acc[16];
        float bias = neuronB[n];
#pragma unroll
        for (int t = 0; t < 16; ++t) acc[t] = bias;
        const f4_t* W4 = reinterpret_cast<const f4_t*>(neuronW);
        f4_t* wst4 = reinterpret_cast<f4_t*>(&sm.a.wst[0][0]);
        for (int c = 0; c < 4; ++c) {
            const int d0 = c * 32;
            __syncthreads();   // wst free (also covers xs16 at c=0)
#pragma unroll
            for (int k = 0; k < 8; ++k) {
                int idx = tid + k * 256;         // 0..2047 float4
                int dd = idx >> 6, j4 = idx & 63;
                wst4[dd * 64 + j4] = W4[(size_t)(d0 + dd) * 1024 + (n0 >> 2) + j4];
            }
            __syncthreads();
#pragma unroll
            for (int dd = 0; dd < 32; ++dd) {
                float w = sm.a.wst[dd][tid];     // conflict-free
#pragma unroll
                for (int t = 0; t < 16; ++t) acc[t] += sm.a.xs16[t][d0 + dd] * w;
            }
        }
#pragma unroll
        for (int t = 0; t < 16; ++t) acc[t] = tanhf(acc[t]);  // |tanh|<=1 => clip no-op
        float denom = 0.1f;
#pragma unroll
        for (int i = 0; i < 6; ++i) denom += ww[i];
        const float inv = 1.f / denom;
        float s1 = acc[15];
        float s2 = s1 + acc[14];
        float s4 = s2 + acc[13] + acc[12];
        float s8 = s4 + acc[11] + acc[10] + acc[9] + acc[8];
        float s16 = s8 + acc[7] + acc[6] + acc[5] + acc[4] + acc[3] + acc[2] + acc[1] + acc[0];
        v[0 * N_NEU + n] = s1 * ((ww[0] + 0.1f) * inv);
        v[1 * N_NEU + n] = s2 * 0.5f * ((ww[1] + 0.1f) * inv);
        v[2 * N_NEU + n] = s4 * 0.25f * ((ww[2] + 0.1f) * inv);
        v[3 * N_NEU + n] = s8 * 0.125f * ((ww[3] + 0.1f) * inv);
        v[4 * N_NEU + n] = s16 * 0.0625f * ((ww[4] + 0.1f) * inv);
        return;
    }

    // ---- blocks 16..18: one q/k/v matrix each, full-W single-burst staging --
    const int m = bid - 16;
    const float* Wm = (m == 0) ? Wq : ((m == 1) ? Wk : Wv);
    const float* bb = (m == 0) ? bq : ((m == 1) ? bk : bv);

    f4_t* xs4 = reinterpret_cast<f4_t*>(&sm.q.xs[0][0]);
    const f4_t* X4 = reinterpret_cast<const f4_t*>(x + (size_t)(T_TOK - 32) * D_DIM);
#pragma unroll
    for (int k = 0; k < 4; ++k) xs4[tid + k * 256] = X4[tid + k * 256];
    f4_t* w4 = reinterpret_cast<f4_t*>(&sm.q.w[0][0]);
    const f4_t* Wm4 = reinterpret_cast<const f4_t*>(Wm);
#pragma unroll
    for (int k = 0; k < 16; ++k) w4[tid + k * 256] = Wm4[tid + k * 256];
    __syncthreads();

    const int d = tid & 127;
    const int g = tid >> 7;
    float acc[16];
    float bias = bb[d];
#pragma unroll
    for (int i = 0; i < 16; ++i) acc[i] = bias;
#pragma unroll 4
    for (int e = 0; e < 128; ++e) {
        float w = sm.q.w[e][d];
#pragma unroll
        for (int i = 0; i < 16; ++i) acc[i] += sm.q.xs[g * 16 + i][e] * w;
    }
#pragma unroll
    for (int i = 0; i < 16; ++i) qkv[m * 4096 + (g * 16 + i) * 128 + d] = acc[i];
}

// ---------------------------------------------------------------------------
// Kernel B: attn chain + proj, fused. 16 blocks x 256. Every block
// REDUNDANTLY recomputes the tiny attention chain (identical math,
// deterministic), then projects its own 256 columns with staged projW
// and writes weighted v row 5.
// ---------------------------------------------------------------------------
struct SmemAP {
    union {
        struct {
            float qs[32][128];
            float kt[128][33];
            float vs[32][128];
            float ps[32][33];
            float pbar[32];
            float mvec[128];
            float red[2];
        } a;
        struct {
            float wst[32][256];
        } p;
    } u;
    float ys[128];   // LayerNorm output, survives the union switch
};

__global__ void attn_proj_kernel(
    const float* __restrict__ qkv,
    const float* __restrict__ ln_g, const float* __restrict__ ln_b,
    const float* __restrict__ projW,   // [128][4096]
    const float* __restrict__ projb,
    const float* __restrict__ ww,
    float* __restrict__ v)             // writes [5*4096 .. 6*4096)
{
    __shared__ SmemAP sm;
    const int tid = threadIdx.x;

    // ---- attention chain (verified structure, rounds 3-8) ----
    for (int idx = tid; idx < 32 * 128; idx += 256) {
        int i = idx >> 7, d = idx & 127;
        sm.u.a.qs[i][d] = qkv[idx];
        sm.u.a.kt[d][i] = qkv[4096 + idx];
        sm.u.a.vs[i][d] = qkv[8192 + idx];
    }
    __syncthreads();
    const float scale = 0.08838834764831845f;  // 1/sqrt(128)
#pragma unroll
    for (int rep = 0; rep < 4; ++rep) {
        int idx = tid + rep * 256;
        int i = idx >> 5, j = idx & 31;
        float acc = 0.f;
        for (int e = 0; e < 128; ++e) acc += sm.u.a.qs[i][e] * sm.u.a.kt[e][j];
        sm.u.a.ps[i][j] = acc * scale;
    }
    __syncthreads();
    if (tid < 32) {
        float mx = -1e30f;
        for (int j = 0; j < 32; ++j) mx = fmaxf(mx, sm.u.a.ps[tid][j]);
        float s = 0.f;
        for (int j = 0; j < 32; ++j) { float e = expf(sm.u.a.ps[tid][j] - mx); sm.u.a.ps[tid][j] = e; s += e; }
        float inv = 1.f / s;
        for (int j = 0; j < 32; ++j) sm.u.a.ps[tid][j] *= inv;
    }
    __syncthreads();
    if (tid < 32) {
        float s = 0.f;
        for (int i = 0; i < 32; ++i) s += sm.u.a.ps[i][tid];
        sm.u.a.pbar[tid] = s * (1.f / 32.f);
    }
    __syncthreads();
    if (tid < 128) {
        float s = 0.f;
        for (int j = 0; j < 32; ++j) s += sm.u.a.pbar[j] * sm.u.a.vs[j][tid];
        sm.u.a.mvec[tid] = s;
    }
    __syncthreads();
    if (tid < 64) {
        float p = sm.u.a.mvec[tid] + sm.u.a.mvec[tid + 64];
        for (int off = 32; off; off >>= 1) p += __shfl_down(p, off);
        if (tid == 0) sm.u.a.red[0] = p * (1.f / 128.f);
    }
    __syncthreads();
    float mu = sm.u.a.red[0];
    if (tid < 64) {
        float t1 = sm.u.a.mvec[tid] - mu, t2 = sm.u.a.mvec[tid + 64] - mu;
        float p = t1 * t1 + t2 * t2;
        for (int off = 32; off; off >>= 1) p += __shfl_down(p, off);
        if (tid == 0) sm.u.a.red[1] = rsqrtf(p * (1.f / 128.f) + 1e-5f);
    }
    __syncthreads();
    if (tid < 128) {
        sm.ys[tid] = (sm.u.a.mvec[tid] - mu) * sm.u.a.red[1] * ln_g[tid] + ln_b[tid];
    }
    __syncthreads();   // attn LDS now dead; ys live

    // ---- proj for this block's 256 columns (staged projW) ----
    const int n0 = blockIdx.x * 256;
    const int n = n0 + tid;
    float denom = 0.1f;
#pragma unroll
    for (int i = 0; i < 6; ++i) denom += ww[i];
    const float nw5 = (ww[5] + 0.1f) / denom;

    float acc = projb[n];
    const f4_t* P4 = reinterpret_cast<const f4_t*>(projW);
    f4_t* wst4 = reinterpret_cast<f4_t*>(&sm.u.p.wst[0][0]);
    for (int c = 0; c < 4; ++c) {
        const int d0 = c * 32;
        __syncthreads();
#pragma unroll
        for (int k = 0; k < 8; ++k) {
            int idx = tid + k * 256;
            int dd = idx >> 6, j4 = idx & 63;
            wst4[dd * 64 + j4] = P4[(size_t)(d0 + dd) * 1024 + (n0 >> 2) + j4];
        }
        __syncthreads();
#pragma unroll
        for (int dd = 0; dd < 32; ++dd) {
            acc += sm.ys[d0 + dd] * sm.u.p.wst[dd][tid];
        }
    }
    v[5 * N_NEU + n] = acc * nw5;
}

// ---------------------------------------------------------------------------
// Kernel C: combo partials — pure stream with NONTEMPORAL comboW loads
// (bypass LLC allocation; the 402 MB cyclic stream thrashes the 256 MB L3
// and pollutes it for everything else). 512 blocks x 256 threads:
// chunk = bid>>2 (192 rows), coltile = bid&3. Wave: 1 KB contiguous/row.
// ---------------------------------------------------------------------------
__global__ __launch_bounds__(256) void combo_partial_kernel(
    const float* __restrict__ v,       // [24576]
    const float* __restrict__ comboW,  // [24576][4096]
    float* __restrict__ part)          // [NCHUNK][4096]
{
    __shared__ float vsm[RPC];
    const int tid = threadIdx.x;
    const int chunk = blockIdx.x >> 2;
    const int cb = blockIdx.x & 3;
    const int row0 = chunk * RPC;

    if (tid < RPC) vsm[tid] = v[row0 + tid];
    __syncthreads();

    const f4_t* W4 = reinterpret_cast<const f4_t*>(comboW);
    const size_t base = (size_t)row0 * 1024 + cb * 256 + tid;   // float4 index
    f4_t acc = {0.f, 0.f, 0.f, 0.f};
#pragma unroll 8
    for (int r = 0; r < RPC; ++r) {
        f4_t w = __builtin_nontemporal_load(&W4[base + (size_t)r * 1024]);
        acc += w * vsm[r];
    }
    reinterpret_cast<f4_t*>(part)[(size_t)chunk * 1024 + cb * 256 + tid] = acc;
}

// ---------------------------------------------------------------------------
// Kernel D: reduce 128 partials + bias. 16 blocks x 256, f4 cols,
// 4-way chunk split (32-deep) + LDS combine. Reads only 2 MB.
// ---------------------------------------------------------------------------
__global__ void combo_reduce_kernel(const float* __restrict__ part,
                                    const float* __restrict__ bias,
                                    float* __restrict__ out)
{
    __shared__ f4_t red[4][64];
    const int tid = threadIdx.x;
    const int h = tid >> 6;                 // 0..3: chunk quarter (32 each)
    const int j = tid & 63;
    const int n4 = blockIdx.x * 64 + j;
    const f4_t* P4 = reinterpret_cast<const f4_t*>(part);
    f4_t acc = {0.f, 0.f, 0.f, 0.f};
#pragma unroll 8
    for (int c = h * 32; c < h * 32 + 32; ++c)
        acc += P4[(size_t)c * 1024 + n4];
    red[h][j] = acc;
    __syncthreads();
    if (h == 0) {
        f4_t s = red[0][j] + red[1][j] + red[2][j] + red[3][j];
        s += reinterpret_cast<const f4_t*>(bias)[n4];
        reinterpret_cast<f4_t*>(out)[n4] = s;
    }
}

// ---------------------------------------------------------------------------
extern "C" void kernel_launch(void* const* d_in, const int* in_sizes, int n_in,
                              void* d_out, int out_size, void* d_ws, size_t ws_size,
                              hipStream_t stream) {
    const float* inputEmbeds = (const float*)d_in[0];
    const float* neuronW     = (const float*)d_in[1];
    const float* neuronB     = (const float*)d_in[2];
    const float* Wq          = (const float*)d_in[3];
    const float* bq          = (const float*)d_in[4];
    const float* Wk          = (const float*)d_in[5];
    const float* bk          = (const float*)d_in[6];
    const float* Wv          = (const float*)d_in[7];
    const float* bv          = (const float*)d_in[8];
    const float* ln_g        = (const float*)d_in[9];
    const float* ln_b        = (const float*)d_in[10];
    const float* projW       = (const float*)d_in[11];
    const float* projb       = (const float*)d_in[12];
    const float* ww          = (const float*)d_in[13];
    const float* comboW      = (const float*)d_in[14];
    const float* combob      = (const float*)d_in[15];
    float* out = (float*)d_out;
    float* ws  = (float*)d_ws;

    float* v    = ws;                 // 6*4096 = 24576
    float* qkv  = ws + 24576;         // 3*4096 = 12288
    float* part = ws + 36864;         // NCHUNK*4096 = 524288

    acts_qkv_kernel<<<19, 256, 0, stream>>>(inputEmbeds, neuronW, neuronB,
                                            Wq, bq, Wk, bk, Wv, bv, ww, v, qkv);
    attn_proj_kernel<<<16, 256, 0, stream>>>(qkv, ln_g, ln_b, projW, projb, ww, v);
    combo_partial_kernel<<<NCHUNK * 4, 256, 0, stream>>>(v, comboW, part);
    combo_reduce_kernel<<<16, 256, 0, stream>>>(part, combob, out);
}